// Round 1
// baseline (810.889 us; speedup 1.0000x reference)
//
#include <hip/hip_runtime.h>

#define B_SZ  1024
#define N_SEQ 512
#define D_INP 30
#define H     64
#define G4    256   // 4*H
#define ROWS  2
#define TCH   16                 // timesteps of x staged per chunk
#define NCH   (N_SEQ / TCH)      // 32 chunks

__device__ __forceinline__ float sigmoid_f(float x) {
  return 1.0f / (1.0f + __expf(-x));
}
__device__ __forceinline__ float tanh_f(float x) {
  // 1 - 2/(1+e^{2x}); saturates correctly via inf handling
  return 1.0f - 2.0f / (1.0f + __expf(2.0f * x));
}

// ---------------------------------------------------------------------------
// Kernel A: fold FC into the input-side gate GEMM.
// W_comb[u][k] = sum_i W_ih[u][i] * W_fc[i][k]   (256 x 30, stored stride 32)
// b_comb[u]    = sum_i W_ih[u][i] * b_fc[i] + b_ih[u] + b_hh[u]
// ---------------------------------------------------------------------------
__global__ __launch_bounds__(256) void prep_kernel(
    const float* __restrict__ W_fc, const float* __restrict__ b_fc,
    const float* __restrict__ W_ih, const float* __restrict__ b_ih,
    const float* __restrict__ b_hh,
    float* __restrict__ wsW, float* __restrict__ wsB) {
  __shared__ float fc[H * D_INP];
  __shared__ float bfc[H];
  const int u = threadIdx.x;
  for (int i = u; i < H * D_INP; i += 256) fc[i] = W_fc[i];
  if (u < H) bfc[u] = b_fc[u];
  __syncthreads();

  float wih[H];
#pragma unroll
  for (int i = 0; i < H; ++i) wih[i] = W_ih[u * H + i];

  for (int k = 0; k < D_INP; ++k) {
    float s = 0.f;
#pragma unroll
    for (int i = 0; i < H; ++i) s = fmaf(wih[i], fc[i * D_INP + k], s);
    wsW[u * 32 + k] = s;
  }
  wsW[u * 32 + 30] = 0.f;   // zero pad so float4 path multiplies by 0
  wsW[u * 32 + 31] = 0.f;

  float bb = b_ih[u] + b_hh[u];
#pragma unroll
  for (int i = 0; i < H; ++i) bb = fmaf(wih[i], bfc[i], bb);
  wsB[u] = bb;
}

// ---------------------------------------------------------------------------
// Kernel B: fused LSTM over the full sequence + logits + softmax.
// 512 blocks x 256 threads; block owns 2 batch rows. Thread u owns gate-unit
// u: W_hh row + W_comb row in registers. h broadcast via LDS float4 reads.
// ---------------------------------------------------------------------------
__global__ __launch_bounds__(256, 2) void lstm_kernel(
    const float* __restrict__ x, const float* __restrict__ W_hh,
    const float* __restrict__ wsW, const float* __restrict__ wsB,
    const float* __restrict__ W_last, float* __restrict__ out) {
  __shared__ __align__(16) float h_lds[ROWS][H];
  __shared__ float gates[ROWS][G4];
  __shared__ __align__(16) float xs[ROWS][TCH][32];
  __shared__ float logits[ROWS][N_SEQ];

  const int u = threadIdx.x;
  const int b0 = blockIdx.x * ROWS;

  // ---- per-thread weights in registers ----
  float4 whh[16];
  {
    const float4* g = (const float4*)(W_hh + u * H);
#pragma unroll
    for (int q = 0; q < 16; ++q) whh[q] = g[q];
  }
  float4 wcb[8];
  {
    const float4* g = (const float4*)(wsW + u * 32);
#pragma unroll
    for (int q = 0; q < 8; ++q) wcb[q] = g[q];
  }
  const float bcu = wsB[u];

  float wl = 0.f;
  if (u < ROWS * H) wl = W_last[u & (H - 1)];
  float c_reg = 0.f;
  if (u < ROWS * H) h_lds[u >> 6][u & 63] = 0.f;

  // ---- x chunk prefetch helpers (1024 padded floats per chunk) ----
  float pf[4];
  auto load_chunk = [&](int tc, float* p) {
#pragma unroll
    for (int q = 0; q < 4; ++q) {
      int i = u + q * 256;
      int r = i >> 9, rem = i & 511;
      int tt = rem >> 5, k = rem & 31;
      float v = 0.f;
      if (k < D_INP)
        v = x[((size_t)(b0 + r) * N_SEQ + (size_t)(tc * TCH + tt)) * D_INP + k];
      p[q] = v;
    }
  };
  auto store_chunk = [&](const float* p) {
#pragma unroll
    for (int q = 0; q < 4; ++q) {
      int i = u + q * 256;
      int r = i >> 9, rem = i & 511;
      int tt = rem >> 5, k = rem & 31;
      xs[r][tt][k] = p[q];
    }
  };

  load_chunk(0, pf);
  store_chunk(pf);
  __syncthreads();

  const bool isg = (u >= 2 * H) && (u < 3 * H);  // wave 2 => tanh gate

  for (int tc = 0; tc < NCH; ++tc) {
    float pfn[4];
    if (tc + 1 < NCH) load_chunk(tc + 1, pfn);

    for (int tt = 0; tt < TCH; ++tt) {
      // ---- gate preactivations: acc_r = b + h_r.Whh_u + x_r.Wc_u ----
      float acc0 = bcu, acc1 = bcu;
#pragma unroll
      for (int q = 0; q < 16; ++q) {
        float4 w = whh[q];
        float4 a = *(const float4*)&h_lds[0][q * 4];
        float4 b = *(const float4*)&h_lds[1][q * 4];
        acc0 = fmaf(w.x, a.x, acc0); acc0 = fmaf(w.y, a.y, acc0);
        acc0 = fmaf(w.z, a.z, acc0); acc0 = fmaf(w.w, a.w, acc0);
        acc1 = fmaf(w.x, b.x, acc1); acc1 = fmaf(w.y, b.y, acc1);
        acc1 = fmaf(w.z, b.z, acc1); acc1 = fmaf(w.w, b.w, acc1);
      }
#pragma unroll
      for (int q = 0; q < 8; ++q) {
        float4 w = wcb[q];
        float4 a = *(const float4*)&xs[0][tt][q * 4];
        float4 b = *(const float4*)&xs[1][tt][q * 4];
        acc0 = fmaf(w.x, a.x, acc0); acc0 = fmaf(w.y, a.y, acc0);
        acc0 = fmaf(w.z, a.z, acc0); acc0 = fmaf(w.w, a.w, acc0);
        acc1 = fmaf(w.x, b.x, acc1); acc1 = fmaf(w.y, b.y, acc1);
        acc1 = fmaf(w.z, b.z, acc1); acc1 = fmaf(w.w, b.w, acc1);
      }
      float g0, g1;
      if (isg) { g0 = tanh_f(acc0); g1 = tanh_f(acc1); }
      else     { g0 = sigmoid_f(acc0); g1 = sigmoid_f(acc1); }
      gates[0][u] = g0;
      gates[1][u] = g1;
      __syncthreads();

      // ---- state update: thread u<128 owns element (r=u>>6, j=u&63) ----
      if (u < ROWS * H) {
        const int r = u >> 6, j = u & 63;
        float gi = gates[r][j];
        float gf = gates[r][H + j];
        float gg = gates[r][2 * H + j];
        float go = gates[r][3 * H + j];
        c_reg = fmaf(gf, c_reg, gi * gg);
        float h = go * tanh_f(c_reg);
        h_lds[r][j] = h;
        float wsum = h * wl;   // logit contribution; b_last cancels in softmax
#pragma unroll
        for (int m = 32; m >= 1; m >>= 1) wsum += __shfl_xor(wsum, m, 64);
        if (j == 0) logits[r][tc * TCH + tt] = wsum;
      }
      __syncthreads();
    }

    if (tc + 1 < NCH) {
      store_chunk(pfn);   // xs reads for chunk tc all completed at last barrier
      __syncthreads();
    }
  }

  // ---- softmax over time, one wave per batch row ----
  __syncthreads();
  if (u < ROWS * H) {
    const int r = u >> 6, j = u & 63;
    float l[8], vmax = -3.0e38f;
#pragma unroll
    for (int s = 0; s < 8; ++s) {
      l[s] = logits[r][j + 64 * s];
      vmax = fmaxf(vmax, l[s]);
    }
#pragma unroll
    for (int m = 32; m >= 1; m >>= 1) vmax = fmaxf(vmax, __shfl_xor(vmax, m, 64));
    float e[8], sum = 0.f;
#pragma unroll
    for (int s = 0; s < 8; ++s) { e[s] = __expf(l[s] - vmax); sum += e[s]; }
#pragma unroll
    for (int m = 32; m >= 1; m >>= 1) sum += __shfl_xor(sum, m, 64);
    float inv = 1.0f / sum;
#pragma unroll
    for (int s = 0; s < 8; ++s)
      out[(size_t)(b0 + r) * N_SEQ + j + 64 * s] = e[s] * inv;
  }
}

// ---------------------------------------------------------------------------
extern "C" void kernel_launch(void* const* d_in, const int* in_sizes, int n_in,
                              void* d_out, int out_size, void* d_ws, size_t ws_size,
                              hipStream_t stream) {
  const float* x      = (const float*)d_in[0];
  const float* W_fc   = (const float*)d_in[1];
  const float* b_fc   = (const float*)d_in[2];
  const float* W_ih   = (const float*)d_in[3];
  const float* W_hh   = (const float*)d_in[4];
  const float* b_ih   = (const float*)d_in[5];
  const float* b_hh   = (const float*)d_in[6];
  const float* W_last = (const float*)d_in[7];
  // d_in[8] = b_last: constant shift, cancels in softmax.

  float* out = (float*)d_out;
  float* wsW = (float*)d_ws;        // 256*32 floats (padded combined weight)
  float* wsB = wsW + G4 * 32;       // 256 floats

  prep_kernel<<<1, 256, 0, stream>>>(W_fc, b_fc, W_ih, b_ih, b_hh, wsW, wsB);
  lstm_kernel<<<B_SZ / ROWS, 256, 0, stream>>>(x, W_hh, wsW, wsB, W_last, out);
}